// Round 4
// baseline (201.771 us; speedup 1.0000x reference)
//
#include <hip/hip_runtime.h>

#define N_NODES 50000
#define N_EDGES 640000
#define N_SUP   3
#define D       128
#define NTOT    150000                   // 3 * 50000 global rows
#define E_TOT   1920000
#define NC      293                      // 512-row coarse buckets (grow>>9)
#define CAPC    7680                     // per-bucket cap: mean 6553 + ~14 sigma
#define CTILE   2048
#define CTPS    313                      // ceil(640000/2048) tiles per support
#define SBLKS   (N_SUP * CTPS)           // 939 edge tiles
#define HP      320                      // tileHist row pitch (NC padded)
#define XCBLKS  3125                     // (50000*128/4)/512 x-convert blocks
#define WBLKS   96                       // 49152/512 W-pack blocks
#define LDSTR   132                      // LDS row stride in shorts (128+4 pad)

typedef __attribute__((ext_vector_type(2))) float f32x2;
typedef __attribute__((ext_vector_type(4))) float f32x4;
typedef __attribute__((ext_vector_type(8))) short s16x8;

__device__ __forceinline__ unsigned short f2bf(float f) {   // RNE
    unsigned int u = __float_as_uint(f);
    u += 0x7FFFu + ((u >> 16) & 1u);
    return (unsigned short)(u >> 16);
}

// ---------------------------------------------------------------------------
// Pass 1: per-tile bucket HISTOGRAM (LDS only, coalesced global write of the
// 293 counts -- NO global atomics), fused with x->bf16 / W->fragment
// converts. R3's prep paid a ~939-deep cross-XCD atomic RMW chain per
// coarse counter; this pass + scan_tiles replace it deterministically.
// ---------------------------------------------------------------------------
__global__ __launch_bounds__(512) void hist_convert(
    const int* __restrict__ rows, int* __restrict__ tileHist,
    const float4* __restrict__ x, ushort4* __restrict__ xb,
    const float* __restrict__ W, unsigned short* __restrict__ Wf)
{
    int tid = threadIdx.x;

    if (blockIdx.x >= SBLKS) {                   // -------- convert path ----
        int gid = (blockIdx.x - SBLKS) * 512 + tid;
        if (gid < N_NODES * D / 4) {             // x -> bf16
            float4 v = x[gid];
            ushort4 o;
            o.x = f2bf(v.x); o.y = f2bf(v.y); o.z = f2bf(v.z); o.w = f2bf(v.w);
            xb[gid] = o;
        } else {                                 // W -> MFMA B-fragment order
            int g2 = gid - N_NODES * D / 4;
            if (g2 < N_SUP * D * D) {
                int j    = g2 & 7;
                int lane = (g2 >> 3) & 63;
                int rest = g2 >> 9;
                int nt = rest & 7, kb = (rest >> 3) & 3, s = rest >> 5;
                int k = kb * 32 + ((lane >> 4) * 8) + j;
                int n = nt * 16 + (lane & 15);
                Wf[g2] = f2bf(W[((size_t)s * D + k) * D + n]);
            }
        }
        return;
    }

    __shared__ int h[512];
    h[tid] = 0;
    __syncthreads();

    int s  = blockIdx.x / CTPS;
    int tb = (blockIdx.x % CTPS) * CTILE;
    int n  = N_EDGES - tb; if (n > CTILE) n = CTILE;
    const int* rp = rows + (size_t)s * N_EDGES + tb;

    #pragma unroll
    for (int i = 0; i < 4; ++i) {
        int idx = tid + i * 512;
        if (idx < n) atomicAdd(&h[(s * N_NODES + rp[idx]) >> 9], 1);
    }
    __syncthreads();
    if (tid < NC) tileHist[(size_t)blockIdx.x * HP + tid] = h[tid];
}

// ---------------------------------------------------------------------------
// Pass 2: per-bucket exclusive scan over tiles. Block b scans
// tileHist[0..938][b] in place (2 elements/thread, wave shfl scan + 8 wave
// sums, 2 barriers) -> deterministic (tile,bucket) bases + bucket totals.
// ---------------------------------------------------------------------------
__global__ __launch_bounds__(512) void scan_tiles(
    int* __restrict__ tileHist, int* __restrict__ bucketCnt)
{
    __shared__ int wsum[8];
    int b    = blockIdx.x;
    int tid  = threadIdx.x;
    int lane = tid & 63;
    int w    = tid >> 6;
    int t0   = 2 * tid, t1 = 2 * tid + 1;

    int a = (t0 < SBLKS) ? tileHist[(size_t)t0 * HP + b] : 0;
    int c = (t1 < SBLKS) ? tileHist[(size_t)t1 * HP + b] : 0;
    int s = a + c;

    int v = s;                                   // wave inclusive scan
    #pragma unroll
    for (int d = 1; d < 64; d <<= 1) {
        int t = __shfl_up(v, d);
        v += (lane >= d) ? t : 0;
    }
    if (lane == 63) wsum[w] = v;
    __syncthreads();
    int add = 0;
    #pragma unroll
    for (int i = 0; i < 8; ++i) add += (i < w) ? wsum[i] : 0;
    int incl = v + add;
    int excl = incl - s;

    if (t0 < SBLKS) tileHist[(size_t)t0 * HP + b] = excl;
    if (t1 < SBLKS) tileHist[(size_t)t1 * HP + b] = excl + a;
    if (tid == 511) bucketCnt[b] = incl;
}

// ---------------------------------------------------------------------------
// Pass 3: coarse SCATTER (deterministic). Identical LDS ranking + staging to
// R3's prep_scatter, but the global bucket base comes from the scanned
// tileHist row (coalesced load) instead of a cross-XCD atomicAdd. Zero
// global atomics. meta = (local_row<<16) | col.
// ---------------------------------------------------------------------------
__global__ __launch_bounds__(512) void scatter(
    const int* __restrict__ rows, const int* __restrict__ cols,
    const float* __restrict__ vals, const int* __restrict__ tileHist,
    unsigned int* __restrict__ sortedM, unsigned short* __restrict__ sortedV)
{
    __shared__ int            h[512];            // bucket histogram
    __shared__ int            toff[512];         // tile-local bucket offsets
    __shared__ int            gbase[512];        // scanned (tile,bucket) bases
    __shared__ int            wsum[8];
    __shared__ unsigned int   stageM[CTILE];     // 8 KB bucket-sorted meta
    __shared__ unsigned short stageV[CTILE];     // 4 KB bucket-sorted bf16 val
    __shared__ unsigned int   dst[CTILE];        // 8 KB absolute dests

    int tid  = threadIdx.x;
    const int lane = tid & 63;
    const int w    = tid >> 6;

    h[tid] = 0;
    if (tid < NC) gbase[tid] = tileHist[(size_t)blockIdx.x * HP + tid];
    __syncthreads();

    int s  = blockIdx.x / CTPS;
    int tb = (blockIdx.x % CTPS) * CTILE;
    int n  = N_EDGES - tb; if (n > CTILE) n = CTILE;
    const int*   rp = rows + (size_t)s * N_EDGES + tb;
    const int*   cp = cols + (size_t)s * N_EDGES + tb;
    const float* vp = vals + (size_t)s * N_EDGES + tb;

    int bk[4], rk[4]; unsigned int edM[4]; unsigned short edV[4];
    #pragma unroll
    for (int i = 0; i < 4; ++i) {
        int idx = tid + i * 512;
        bk[i] = -1;
        if (idx < n) {
            int grow = s * N_NODES + rp[idx];
            bk[i] = grow >> 9;
            rk[i] = atomicAdd(&h[bk[i]], 1);     // within-tile bucket rank (LDS)
            edM[i] = ((unsigned int)(grow & 511) << 16) | (unsigned int)cp[idx];
            edV[i] = f2bf(vp[idx]);
        }
    }
    __syncthreads();
    int cntb = h[tid];

    int v = cntb;                                // wave inclusive scan
    #pragma unroll
    for (int d = 1; d < 64; d <<= 1) {
        int t = __shfl_up(v, d);
        v += (lane >= d) ? t : 0;
    }
    if (lane == 63) wsum[w] = v;
    __syncthreads();
    int add = 0;
    #pragma unroll
    for (int i = 0; i < 8; ++i) add += (i < w) ? wsum[i] : 0;
    toff[tid] = v + add - cntb;                  // tile-local exclusive
    __syncthreads();

    #pragma unroll
    for (int i = 0; i < 4; ++i) {
        if (bk[i] >= 0) {
            int slot  = toff[bk[i]] + rk[i];
            int gslot = gbase[bk[i]] + rk[i];    // deterministic global slot
            stageM[slot] = edM[i];
            stageV[slot] = edV[i];
            dst[slot] = (gslot < CAPC)
                      ? (unsigned int)(bk[i] * CAPC + gslot)
                      : 0xFFFFFFFFu;             // never at +14 sigma
        }
    }
    __syncthreads();
    for (int j = tid; j < n; j += 512) {         // coalesced run writes
        unsigned int d = dst[j];
        if (d != 0xFFFFFFFFu) {
            sortedM[d] = stageM[j];
            sortedV[d] = stageV[j];
        }
    }
}

// ---------------------------------------------------------------------------
// Pass 4: fine sort, ONE block per bucket, now 1024 threads (R3 ran 512 ->
// 1.14 blocks/CU = 25% occupancy, latency-bound serial chain; 1024 threads
// doubles resident waves to hide load/LDS-atomic latency). 8 regs/thread.
// row_ptr2: 513 entries/bucket, last = bucket end.
// ---------------------------------------------------------------------------
__global__ __launch_bounds__(1024) void bucket_sort(
    const int* __restrict__ bucketCnt,
    const unsigned int* __restrict__ sortedM,
    const unsigned short* __restrict__ sortedV,
    int* __restrict__ row_ptr2, unsigned int* __restrict__ sortedB)
{
    int c   = blockIdx.x;
    int cnt = bucketCnt[c];
    if (cnt > CAPC) cnt = CAPC;

    __shared__ int hist[512];
    __shared__ int rank[512];
    __shared__ int wsum[8];
    int tid  = threadIdx.x;
    int lane = tid & 63;
    int w    = tid >> 6;
    if (tid < 512) hist[tid] = 0;

    const unsigned int*   srcM = sortedM + (size_t)c * CAPC;
    const unsigned short* srcV = sortedV + (size_t)c * CAPC;
    unsigned int   m[8];
    unsigned short vv[8];
    #pragma unroll
    for (int k = 0; k < 8; ++k) {                // independent loads
        int idx = tid + k * 1024;
        if (idx < cnt) { m[k] = srcM[idx]; vv[k] = srcV[idx]; }
    }
    __syncthreads();
    #pragma unroll
    for (int k = 0; k < 8; ++k) {
        int idx = tid + k * 1024;
        if (idx < cnt) atomicAdd(&hist[m[k] >> 16], 1);
    }
    __syncthreads();

    int cntb = 0, v = 0;
    if (tid < 512) {
        cntb = hist[tid];
        v = cntb;                                // wave inclusive scan
        #pragma unroll
        for (int d = 1; d < 64; d <<= 1) {
            int t = __shfl_up(v, d);
            v += (lane >= d) ? t : 0;
        }
        if (lane == 63) wsum[w] = v;
    }
    __syncthreads();
    if (tid < 512) {
        int add = 0;
        #pragma unroll
        for (int i = 0; i < 8; ++i) add += (i < w) ? wsum[i] : 0;
        int incl  = v + add;
        int start = c * CAPC + incl - cntb;      // exclusive, bucket-based
        rank[tid] = start;
        row_ptr2[c * 513 + tid] = start;
        if (tid == 511) row_ptr2[c * 513 + 512] = c * CAPC + incl;
    }
    __syncthreads();

    #pragma unroll
    for (int k = 0; k < 8; ++k) {
        int idx = tid + k * 1024;
        if (idx < cnt) {
            int r = atomicAdd(&rank[m[k] >> 16], 1);
            sortedB[r] = ((unsigned int)vv[k] << 16) | (m[k] & 0xFFFFu);
        }
    }
}

// ---------------------------------------------------------------------------
// FUSED gather + MFMA GEMM (proven, untouched). Block = 16 output nodes;
// 4 waves gather 48 rows into a 12.7 KB LDS tile, one barrier, then 24
// MFMAs/wave with fused bias+relu. Inner loop zero-guards lanes >= m, so
// unpadded rows (any edge count) are handled correctly.
// ---------------------------------------------------------------------------
__global__ __launch_bounds__(256) void gather_gemm(
    const unsigned short* __restrict__ xb, const int* __restrict__ row_ptr2,
    const unsigned int* __restrict__ sortedB,
    const unsigned short* __restrict__ Wf,
    const float* __restrict__ bias, float* __restrict__ out)
{
    __shared__ unsigned short ys[48 * LDSTR];    // 12.7 KB
    __shared__ int rs[48], re[48];
    const int tid  = threadIdx.x;
    const int w    = tid >> 6;
    const int lane = tid & 63;
    const int m0   = blockIdx.x * 16;

    if (tid < 48) {
        int grow = (tid >> 4) * N_NODES + m0 + (tid & 15);
        int rpi  = (grow >> 9) * 513 + (grow & 511);
        rs[tid] = row_ptr2[rpi];
        re[tid] = row_ptr2[rpi + 1];
    }
    __syncthreads();

    // ---- phase 1: gather 12 rows per wave ----
    const int hh = lane >> 5;                    // half index
    const int u  = lane & 31;                    // cols 4u..4u+3
    for (int r = w; r < 48; r += 4) {
        int start = rs[r], end = re[r];
        f32x2 accA = {0.f, 0.f}, accB = {0.f, 0.f};
        for (int j = start; j < end; j += 64) {
            int m = end - j; if (m > 64) m = 64;
            unsigned int ev = (lane < m) ? sortedB[j + lane] : 0u;
            for (int t = 0; t < m; t += 4) {
                unsigned int e0 = (unsigned int)__shfl((int)ev, t + hh);
                unsigned int e1 = (unsigned int)__shfl((int)ev, t + 2 + hh);
                float v0 = __uint_as_float(e0 & 0xFFFF0000u);
                float v1 = __uint_as_float(e1 & 0xFFFF0000u);
                uint2 X0 = *((const uint2*)(xb + (size_t)(e0 & 0xFFFFu) * D) + u);
                uint2 X1 = *((const uint2*)(xb + (size_t)(e1 & 0xFFFFu) * D) + u);
                f32x2 xa0 = {__uint_as_float(X0.x << 16),
                             __uint_as_float(X0.x & 0xFFFF0000u)};
                f32x2 xb0 = {__uint_as_float(X0.y << 16),
                             __uint_as_float(X0.y & 0xFFFF0000u)};
                f32x2 xa1 = {__uint_as_float(X1.x << 16),
                             __uint_as_float(X1.x & 0xFFFF0000u)};
                f32x2 xb1 = {__uint_as_float(X1.y << 16),
                             __uint_as_float(X1.y & 0xFFFF0000u)};
                accA += v0 * xa0;                // v_pk_fma_f32
                accB += v0 * xb0;
                accA += v1 * xa1;
                accB += v1 * xb1;
            }
        }
        float a0 = accA.x, a1 = accA.y, a2 = accB.x, a3 = accB.y;
        a0 += __shfl_xor(a0, 32);
        a1 += __shfl_xor(a1, 32);
        a2 += __shfl_xor(a2, 32);
        a3 += __shfl_xor(a3, 32);
        if (hh == 0) {
            uint2 o;
            o.x = (unsigned int)f2bf(a0) | ((unsigned int)f2bf(a1) << 16);
            o.y = (unsigned int)f2bf(a2) | ((unsigned int)f2bf(a3) << 16);
            *(uint2*)(ys + r * LDSTR + u * 4) = o;   // 8B-aligned, 2-way free
        }
    }
    __syncthreads();

    // ---- phase 2: MFMA GEMM, wave w -> nt {2w, 2w+1} ----
    const int quad = lane >> 4;
    const int l16  = lane & 15;
    const int nt0  = w * 2;
    f32x4 acc0 = {0.f, 0.f, 0.f, 0.f}, acc1 = {0.f, 0.f, 0.f, 0.f};

    #pragma unroll
    for (int s = 0; s < N_SUP; ++s) {
        #pragma unroll
        for (int kb = 0; kb < 4; ++kb) {
            union { uint2 q[2]; s16x8 v; } A;
            const unsigned short* ap = ys + (s * 16 + l16) * LDSTR
                                          + kb * 32 + quad * 8;
            A.q[0] = *(const uint2*)ap;          // 8B-aligned LDS reads
            A.q[1] = *(const uint2*)(ap + 4);
            const unsigned short* wf = Wf + (size_t)((s * 4 + kb) * 8 + nt0) * 64 * 8
                                          + lane * 8;
            s16x8 b0 = *(const s16x8*)wf;
            s16x8 b1 = *(const s16x8*)(wf + 64 * 8);
            acc0 = __builtin_amdgcn_mfma_f32_16x16x32_bf16(A.v, b0, acc0, 0, 0, 0);
            acc1 = __builtin_amdgcn_mfma_f32_16x16x32_bf16(A.v, b1, acc1, 0, 0, 0);
        }
    }

    #pragma unroll
    for (int p = 0; p < 2; ++p) {
        int col = (nt0 + p) * 16 + l16;
        float bv = bias[col];
        f32x4 a = p ? acc1 : acc0;
        #pragma unroll
        for (int r = 0; r < 4; ++r) {
            int row = m0 + quad * 4 + r;
            out[(size_t)row * D + col] = fmaxf(a[r] + bv, 0.f);
        }
    }
}

extern "C" void kernel_launch(void* const* d_in, const int* in_sizes, int n_in,
                              void* d_out, int out_size, void* d_ws, size_t ws_size,
                              hipStream_t stream)
{
    const float* x         = (const float*)d_in[0];
    const int*   edge_rows = (const int*)  d_in[1];
    const int*   edge_cols = (const int*)  d_in[2];
    const float* edge_vals = (const float*)d_in[3];
    const float* weights   = (const float*)d_in[4];
    const float* bias      = (const float*)d_in[5];
    float* out = (float*)d_out;

    // workspace layout (256B aligned), ~29 MB total
    char* ws = (char*)d_ws;
    size_t off = 0;
    auto alloc = [&](size_t bytes) -> char* {
        char* p = ws + off;
        off += (bytes + 255) & ~(size_t)255;
        return p;
    };
    int*            tileHist  = (int*)            alloc((size_t)SBLKS * HP * 4);
    int*            bucketCnt = (int*)            alloc((size_t)NC * 4);
    int*            row_ptr2  = (int*)            alloc((size_t)NC * 513 * 4);
    unsigned short* xb        = (unsigned short*) alloc((size_t)N_NODES * D * 2);
    unsigned short* Wf        = (unsigned short*) alloc((size_t)N_SUP * D * D * 2);
    unsigned int*   sortedM   = (unsigned int*)   alloc((size_t)NC * CAPC * 4);
    unsigned short* sortedV   = (unsigned short*) alloc((size_t)NC * CAPC * 2);
    unsigned int*   sortedB   = (unsigned int*)   alloc((size_t)NC * CAPC * 4);

    // no memset needed: every tileHist/bucketCnt entry is written before read
    hist_convert<<<SBLKS + XCBLKS + WBLKS, 512, 0, stream>>>(
        edge_rows, tileHist, (const float4*)x, (ushort4*)xb, weights, Wf);
    scan_tiles  <<<NC, 512, 0, stream>>>(tileHist, bucketCnt);
    scatter     <<<SBLKS, 512, 0, stream>>>(edge_rows, edge_cols, edge_vals,
                                            tileHist, sortedM, sortedV);
    bucket_sort <<<NC, 1024, 0, stream>>>(bucketCnt, sortedM, sortedV,
                                          row_ptr2, sortedB);
    gather_gemm <<<N_NODES / 16, 256, 0, stream>>>(xb, row_ptr2, sortedB,
                                                   Wf, bias, out);
}

// Round 5
// 195.484 us; speedup vs baseline: 1.0322x; 1.0322x over previous
//
#include <hip/hip_runtime.h>

#define N_NODES 50000
#define N_EDGES 640000
#define N_SUP   3
#define D       128
#define NTOT    150000                   // 3 * 50000 global rows
#define E_TOT   1920000
#define NC      293                      // 512-row coarse buckets (grow>>9)
#define CAPC    7680                     // per-bucket cap: mean 6553 + ~14 sigma
#define CTILE   2048
#define CTPS    313                      // ceil(640000/2048) tiles per support
#define SBLKS   (N_SUP * CTPS)           // 939 edge tiles
#define XCBLKS  3125                     // (50000*128/4)/512 x-convert blocks
#define WBLKS   96                       // 49152/512 W-pack blocks
#define LDSTR   132                      // LDS row stride in shorts (128+4 pad)

typedef __attribute__((ext_vector_type(2))) float f32x2;
typedef __attribute__((ext_vector_type(4))) float f32x4;
typedef __attribute__((ext_vector_type(8))) short s16x8;

__device__ __forceinline__ unsigned short f2bf(float f) {   // RNE
    unsigned int u = __float_as_uint(f);
    u += 0x7FFFu + ((u >> 16) & 1u);
    return (unsigned short)(u >> 16);
}

// ---------------------------------------------------------------------------
// Pass 1: coarse scatter ONLY (converts moved out -- they used to delay the
// dependent bucket_sort launch by their ~12 us tail while feeding only
// gather). LDS-staged bucket-sorted runs, atomic global bucket bases
// (R0/R3-proven: the atomic chain costs nothing vs the deterministic scan
// version). stage = uint2 { (local_row<<16)|col, bf16(val)<<16 } -- single
// 8-B store/load per edge instead of R3's 4+2 split.
// ---------------------------------------------------------------------------
__global__ __launch_bounds__(512) void prep_scatter(
    const int* __restrict__ rows, const int* __restrict__ cols,
    const float* __restrict__ vals, int* __restrict__ coarse_wptr,
    uint2* __restrict__ sortedA)
{
    __shared__ int          h[512];              // bucket histogram
    __shared__ int          toff[512];           // tile-local bucket offsets
    __shared__ int          gbase[512];          // global bucket bases
    __shared__ int          wsum[8];
    __shared__ uint2        stage[CTILE];        // 16 KB bucket-sorted edges
    __shared__ unsigned int dst[CTILE];          // 8 KB absolute dests

    int tid  = threadIdx.x;
    const int lane = tid & 63;
    const int w    = tid >> 6;

    h[tid] = 0;
    __syncthreads();

    int s  = blockIdx.x / CTPS;
    int tb = (blockIdx.x % CTPS) * CTILE;
    int n  = N_EDGES - tb; if (n > CTILE) n = CTILE;
    const int*   rp = rows + (size_t)s * N_EDGES + tb;
    const int*   cp = cols + (size_t)s * N_EDGES + tb;
    const float* vp = vals + (size_t)s * N_EDGES + tb;

    int bk[4], rk[4]; uint2 ed[4];
    #pragma unroll
    for (int i = 0; i < 4; ++i) {
        int idx = tid + i * 512;
        bk[i] = -1;
        if (idx < n) {
            int grow = s * N_NODES + rp[idx];
            bk[i] = grow >> 9;
            rk[i] = atomicAdd(&h[bk[i]], 1);     // within-tile bucket rank (LDS)
            ed[i] = make_uint2(((unsigned int)(grow & 511) << 16)
                               | (unsigned int)cp[idx],
                               (unsigned int)f2bf(vp[idx]) << 16);
        }
    }
    __syncthreads();
    int cntb = h[tid];

    int v = cntb;                                // wave inclusive scan
    #pragma unroll
    for (int d = 1; d < 64; d <<= 1) {
        int t = __shfl_up(v, d);
        v += (lane >= d) ? t : 0;
    }
    if (lane == 63) wsum[w] = v;
    __syncthreads();
    int add = 0;
    #pragma unroll
    for (int i = 0; i < 8; ++i) add += (i < w) ? wsum[i] : 0;
    int incl = v + add;

    toff[tid]  = incl - cntb;                    // tile-local exclusive
    gbase[tid] = (cntb > 0) ? atomicAdd(&coarse_wptr[tid * 16], cntb) : 0;
    __syncthreads();

    #pragma unroll
    for (int i = 0; i < 4; ++i) {
        if (bk[i] >= 0) {
            int slot  = toff[bk[i]] + rk[i];
            int gslot = gbase[bk[i]] + rk[i];
            stage[slot] = ed[i];
            dst[slot] = (gslot < CAPC)
                      ? (unsigned int)(bk[i] * CAPC + gslot)
                      : 0xFFFFFFFFu;             // never at +14 sigma
        }
    }
    __syncthreads();
    for (int j = tid; j < n; j += 512) {         // coalesced run writes
        unsigned int d = dst[j];
        if (d != 0xFFFFFFFFu) sortedA[d] = stage[j];
    }
}

// ---------------------------------------------------------------------------
// Pass 2: fine sort (blocks 0..NC-1, latency-bound) co-launched with the
// x->bf16 / W->fragment converts (blocks NC..) -- the BW-bound convert blocks
// overlap the sort blocks' latency chains instead of serializing before
// bucket_sort as in R0/R3. Sort: bucket edges into registers (<=15 uint2),
// LDS histogram + wave scan, rank-scatter. Rows unpadded (gather zero-guards
// lanes >= m). row_ptr2: 513 entries/bucket, last = bucket end.
// ---------------------------------------------------------------------------
__global__ __launch_bounds__(512) void sort_convert(
    const int* __restrict__ coarse_wptr, const uint2* __restrict__ sortedA,
    int* __restrict__ row_ptr2, unsigned int* __restrict__ sortedB,
    const float4* __restrict__ x, ushort4* __restrict__ xb,
    const float* __restrict__ W, unsigned short* __restrict__ Wf)
{
    int tid = threadIdx.x;

    if (blockIdx.x >= NC) {                      // -------- convert path ----
        int gid = (blockIdx.x - NC) * 512 + tid;
        if (gid < N_NODES * D / 4) {             // x -> bf16
            float4 v = x[gid];
            ushort4 o;
            o.x = f2bf(v.x); o.y = f2bf(v.y); o.z = f2bf(v.z); o.w = f2bf(v.w);
            xb[gid] = o;
        } else {                                 // W -> MFMA B-fragment order
            int g2 = gid - N_NODES * D / 4;
            if (g2 < N_SUP * D * D) {
                int j    = g2 & 7;
                int lane = (g2 >> 3) & 63;
                int rest = g2 >> 9;
                int nt = rest & 7, kb = (rest >> 3) & 3, s = rest >> 5;
                int k = kb * 32 + ((lane >> 4) * 8) + j;
                int n = nt * 16 + (lane & 15);
                Wf[g2] = f2bf(W[((size_t)s * D + k) * D + n]);
            }
        }
        return;
    }

    // ------------------------------- sort path ----------------------------
    int c   = blockIdx.x;
    int cnt = coarse_wptr[c * 16];
    if (cnt > CAPC) cnt = CAPC;

    __shared__ int hist[512];
    __shared__ int rank[512];
    __shared__ int wsum[8];
    int lane = tid & 63;
    int w    = tid >> 6;
    hist[tid] = 0;

    const uint2* src = sortedA + (size_t)c * CAPC;
    uint2 e[15];
    #pragma unroll
    for (int k = 0; k < 15; ++k) {               // independent loads
        int idx = tid + k * 512;
        if (idx < cnt) e[k] = src[idx];
    }
    __syncthreads();
    #pragma unroll
    for (int k = 0; k < 15; ++k) {
        int idx = tid + k * 512;
        if (idx < cnt) atomicAdd(&hist[e[k].x >> 16], 1);
    }
    __syncthreads();

    int cntb = hist[tid];
    int v = cntb;                                // wave inclusive scan
    #pragma unroll
    for (int d = 1; d < 64; d <<= 1) {
        int t = __shfl_up(v, d);
        v += (lane >= d) ? t : 0;
    }
    if (lane == 63) wsum[w] = v;
    __syncthreads();
    int add = 0;
    #pragma unroll
    for (int i = 0; i < 8; ++i) add += (i < w) ? wsum[i] : 0;
    int incl = v + add;

    int start = c * CAPC + incl - cntb;          // exclusive, bucket-based
    rank[tid] = start;
    row_ptr2[c * 513 + tid] = start;
    if (tid == 511) row_ptr2[c * 513 + 512] = c * CAPC + incl;
    __syncthreads();

    #pragma unroll
    for (int k = 0; k < 15; ++k) {
        int idx = tid + k * 512;
        if (idx < cnt) {
            int r = atomicAdd(&rank[e[k].x >> 16], 1);
            sortedB[r] = (e[k].y & 0xFFFF0000u) | (e[k].x & 0xFFFFu);
        }
    }
}

// ---------------------------------------------------------------------------
// FUSED gather + MFMA GEMM (proven, untouched). Block = 16 output nodes;
// 4 waves gather 48 rows into a 12.7 KB LDS tile, one barrier, then 24
// MFMAs/wave with fused bias+relu. Inner loop zero-guards lanes >= m, so
// unpadded rows (any edge count) are handled correctly.
// ---------------------------------------------------------------------------
__global__ __launch_bounds__(256) void gather_gemm(
    const unsigned short* __restrict__ xb, const int* __restrict__ row_ptr2,
    const unsigned int* __restrict__ sortedB,
    const unsigned short* __restrict__ Wf,
    const float* __restrict__ bias, float* __restrict__ out)
{
    __shared__ unsigned short ys[48 * LDSTR];    // 12.7 KB
    __shared__ int rs[48], re[48];
    const int tid  = threadIdx.x;
    const int w    = tid >> 6;
    const int lane = tid & 63;
    const int m0   = blockIdx.x * 16;

    if (tid < 48) {
        int grow = (tid >> 4) * N_NODES + m0 + (tid & 15);
        int rpi  = (grow >> 9) * 513 + (grow & 511);
        rs[tid] = row_ptr2[rpi];
        re[tid] = row_ptr2[rpi + 1];
    }
    __syncthreads();

    // ---- phase 1: gather 12 rows per wave ----
    const int hh = lane >> 5;                    // half index
    const int u  = lane & 31;                    // cols 4u..4u+3
    for (int r = w; r < 48; r += 4) {
        int start = rs[r], end = re[r];
        f32x2 accA = {0.f, 0.f}, accB = {0.f, 0.f};
        for (int j = start; j < end; j += 64) {
            int m = end - j; if (m > 64) m = 64;
            unsigned int ev = (lane < m) ? sortedB[j + lane] : 0u;
            for (int t = 0; t < m; t += 4) {
                unsigned int e0 = (unsigned int)__shfl((int)ev, t + hh);
                unsigned int e1 = (unsigned int)__shfl((int)ev, t + 2 + hh);
                float v0 = __uint_as_float(e0 & 0xFFFF0000u);
                float v1 = __uint_as_float(e1 & 0xFFFF0000u);
                uint2 X0 = *((const uint2*)(xb + (size_t)(e0 & 0xFFFFu) * D) + u);
                uint2 X1 = *((const uint2*)(xb + (size_t)(e1 & 0xFFFFu) * D) + u);
                f32x2 xa0 = {__uint_as_float(X0.x << 16),
                             __uint_as_float(X0.x & 0xFFFF0000u)};
                f32x2 xb0 = {__uint_as_float(X0.y << 16),
                             __uint_as_float(X0.y & 0xFFFF0000u)};
                f32x2 xa1 = {__uint_as_float(X1.x << 16),
                             __uint_as_float(X1.x & 0xFFFF0000u)};
                f32x2 xb1 = {__uint_as_float(X1.y << 16),
                             __uint_as_float(X1.y & 0xFFFF0000u)};
                accA += v0 * xa0;                // v_pk_fma_f32
                accB += v0 * xb0;
                accA += v1 * xa1;
                accB += v1 * xb1;
            }
        }
        float a0 = accA.x, a1 = accA.y, a2 = accB.x, a3 = accB.y;
        a0 += __shfl_xor(a0, 32);
        a1 += __shfl_xor(a1, 32);
        a2 += __shfl_xor(a2, 32);
        a3 += __shfl_xor(a3, 32);
        if (hh == 0) {
            uint2 o;
            o.x = (unsigned int)f2bf(a0) | ((unsigned int)f2bf(a1) << 16);
            o.y = (unsigned int)f2bf(a2) | ((unsigned int)f2bf(a3) << 16);
            *(uint2*)(ys + r * LDSTR + u * 4) = o;   // 8B-aligned, 2-way free
        }
    }
    __syncthreads();

    // ---- phase 2: MFMA GEMM, wave w -> nt {2w, 2w+1} ----
    const int quad = lane >> 4;
    const int l16  = lane & 15;
    const int nt0  = w * 2;
    f32x4 acc0 = {0.f, 0.f, 0.f, 0.f}, acc1 = {0.f, 0.f, 0.f, 0.f};

    #pragma unroll
    for (int s = 0; s < N_SUP; ++s) {
        #pragma unroll
        for (int kb = 0; kb < 4; ++kb) {
            union { uint2 q[2]; s16x8 v; } A;
            const unsigned short* ap = ys + (s * 16 + l16) * LDSTR
                                          + kb * 32 + quad * 8;
            A.q[0] = *(const uint2*)ap;          // 8B-aligned LDS reads
            A.q[1] = *(const uint2*)(ap + 4);
            const unsigned short* wf = Wf + (size_t)((s * 4 + kb) * 8 + nt0) * 64 * 8
                                          + lane * 8;
            s16x8 b0 = *(const s16x8*)wf;
            s16x8 b1 = *(const s16x8*)(wf + 64 * 8);
            acc0 = __builtin_amdgcn_mfma_f32_16x16x32_bf16(A.v, b0, acc0, 0, 0, 0);
            acc1 = __builtin_amdgcn_mfma_f32_16x16x32_bf16(A.v, b1, acc1, 0, 0, 0);
        }
    }

    #pragma unroll
    for (int p = 0; p < 2; ++p) {
        int col = (nt0 + p) * 16 + l16;
        float bv = bias[col];
        f32x4 a = p ? acc1 : acc0;
        #pragma unroll
        for (int r = 0; r < 4; ++r) {
            int row = m0 + quad * 4 + r;
            out[(size_t)row * D + col] = fmaxf(a[r] + bv, 0.f);
        }
    }
}

extern "C" void kernel_launch(void* const* d_in, const int* in_sizes, int n_in,
                              void* d_out, int out_size, void* d_ws, size_t ws_size,
                              hipStream_t stream)
{
    const float* x         = (const float*)d_in[0];
    const int*   edge_rows = (const int*)  d_in[1];
    const int*   edge_cols = (const int*)  d_in[2];
    const float* edge_vals = (const float*)d_in[3];
    const float* weights   = (const float*)d_in[4];
    const float* bias      = (const float*)d_in[5];
    float* out = (float*)d_out;

    // workspace layout (256B aligned), ~40 MB total
    char* ws = (char*)d_ws;
    size_t off = 0;
    auto alloc = [&](size_t bytes) -> char* {
        char* p = ws + off;
        off += (bytes + 255) & ~(size_t)255;
        return p;
    };
    int*            coarse_wptr = (int*)            alloc(512 * 16 * 4);
    int*            row_ptr2    = (int*)            alloc((size_t)NC * 513 * 4);
    unsigned short* xb          = (unsigned short*) alloc((size_t)N_NODES * D * 2);
    unsigned short* Wf          = (unsigned short*) alloc((size_t)N_SUP * D * D * 2);
    uint2*          sortedA     = (uint2*)          alloc((size_t)NC * CAPC * 8);
    unsigned int*   sortedB     = (unsigned int*)   alloc((size_t)NC * CAPC * 4);

    hipMemsetAsync(coarse_wptr, 0, 512 * 16 * 4, stream);
    prep_scatter<<<SBLKS, 512, 0, stream>>>(
        edge_rows, edge_cols, edge_vals, coarse_wptr, sortedA);
    sort_convert<<<NC + XCBLKS + WBLKS, 512, 0, stream>>>(
        coarse_wptr, sortedA, row_ptr2, sortedB,
        (const float4*)x, (ushort4*)xb, weights, Wf);
    gather_gemm<<<N_NODES / 16, 256, 0, stream>>>(xb, row_ptr2, sortedB,
                                                  Wf, bias, out);
}

// Round 6
// 186.796 us; speedup vs baseline: 1.0802x; 1.0465x over previous
//
#include <hip/hip_runtime.h>

#define N_NODES 50000
#define N_EDGES 640000
#define N_SUP   3
#define D       128
#define NTOT    150000                   // 3 * 50000 global rows
#define E_TOT   1920000
#define NC      293                      // 512-row coarse buckets (grow>>9)
#define CAPC    7680                     // per-bucket cap: mean 6553 + ~14 sigma
#define CTILE   2048
#define CTPS    313                      // ceil(640000/2048) tiles per support
#define SBLKS   (N_SUP * CTPS)           // 939 edge tiles
#define XCBLKS  3125                     // (50000*128/4)/512 x-convert blocks
#define WBLKS   96                       // 49152/512 W-pack blocks
#define LDSTR   132                      // LDS row stride in shorts (128+4 pad)

typedef __attribute__((ext_vector_type(2))) float f32x2;
typedef __attribute__((ext_vector_type(4))) float f32x4;
typedef __attribute__((ext_vector_type(8))) short s16x8;

__device__ __forceinline__ unsigned short f2bf(float f) {   // RNE
    unsigned int u = __float_as_uint(f);
    u += 0x7FFFu + ((u >> 16) & 1u);
    return (unsigned short)(u >> 16);
}

// ---------------------------------------------------------------------------
// Pass 1: coarse scatter (R5-proven, untouched). LDS-staged bucket-sorted
// runs, atomic global bucket bases, uint2 staged edges.
// ---------------------------------------------------------------------------
__global__ __launch_bounds__(512) void prep_scatter(
    const int* __restrict__ rows, const int* __restrict__ cols,
    const float* __restrict__ vals, int* __restrict__ coarse_wptr,
    uint2* __restrict__ sortedA)
{
    __shared__ int          h[512];              // bucket histogram
    __shared__ int          toff[512];           // tile-local bucket offsets
    __shared__ int          gbase[512];          // global bucket bases
    __shared__ int          wsum[8];
    __shared__ uint2        stage[CTILE];        // 16 KB bucket-sorted edges
    __shared__ unsigned int dst[CTILE];          // 8 KB absolute dests

    int tid  = threadIdx.x;
    const int lane = tid & 63;
    const int w    = tid >> 6;

    h[tid] = 0;
    __syncthreads();

    int s  = blockIdx.x / CTPS;
    int tb = (blockIdx.x % CTPS) * CTILE;
    int n  = N_EDGES - tb; if (n > CTILE) n = CTILE;
    const int*   rp = rows + (size_t)s * N_EDGES + tb;
    const int*   cp = cols + (size_t)s * N_EDGES + tb;
    const float* vp = vals + (size_t)s * N_EDGES + tb;

    int bk[4], rk[4]; uint2 ed[4];
    #pragma unroll
    for (int i = 0; i < 4; ++i) {
        int idx = tid + i * 512;
        bk[i] = -1;
        if (idx < n) {
            int grow = s * N_NODES + rp[idx];
            bk[i] = grow >> 9;
            rk[i] = atomicAdd(&h[bk[i]], 1);     // within-tile bucket rank (LDS)
            ed[i] = make_uint2(((unsigned int)(grow & 511) << 16)
                               | (unsigned int)cp[idx],
                               (unsigned int)f2bf(vp[idx]) << 16);
        }
    }
    __syncthreads();
    int cntb = h[tid];

    int v = cntb;                                // wave inclusive scan
    #pragma unroll
    for (int d = 1; d < 64; d <<= 1) {
        int t = __shfl_up(v, d);
        v += (lane >= d) ? t : 0;
    }
    if (lane == 63) wsum[w] = v;
    __syncthreads();
    int add = 0;
    #pragma unroll
    for (int i = 0; i < 8; ++i) add += (i < w) ? wsum[i] : 0;
    int incl = v + add;

    toff[tid]  = incl - cntb;                    // tile-local exclusive
    gbase[tid] = (cntb > 0) ? atomicAdd(&coarse_wptr[tid * 16], cntb) : 0;
    __syncthreads();

    #pragma unroll
    for (int i = 0; i < 4; ++i) {
        if (bk[i] >= 0) {
            int slot  = toff[bk[i]] + rk[i];
            int gslot = gbase[bk[i]] + rk[i];
            stage[slot] = ed[i];
            dst[slot] = (gslot < CAPC)
                      ? (unsigned int)(bk[i] * CAPC + gslot)
                      : 0xFFFFFFFFu;             // never at +14 sigma
        }
    }
    __syncthreads();
    for (int j = tid; j < n; j += 512) {         // coalesced run writes
        unsigned int d = dst[j];
        if (d != 0xFFFFFFFFu) sortedA[d] = stage[j];
    }
}

// ---------------------------------------------------------------------------
// Pass 2: fine sort co-launched with converts (R5-proven, untouched).
// ---------------------------------------------------------------------------
__global__ __launch_bounds__(512) void sort_convert(
    const int* __restrict__ coarse_wptr, const uint2* __restrict__ sortedA,
    int* __restrict__ row_ptr2, unsigned int* __restrict__ sortedB,
    const float4* __restrict__ x, ushort4* __restrict__ xb,
    const float* __restrict__ W, unsigned short* __restrict__ Wf)
{
    int tid = threadIdx.x;

    if (blockIdx.x >= NC) {                      // -------- convert path ----
        int gid = (blockIdx.x - NC) * 512 + tid;
        if (gid < N_NODES * D / 4) {             // x -> bf16
            float4 v = x[gid];
            ushort4 o;
            o.x = f2bf(v.x); o.y = f2bf(v.y); o.z = f2bf(v.z); o.w = f2bf(v.w);
            xb[gid] = o;
        } else {                                 // W -> MFMA B-fragment order
            int g2 = gid - N_NODES * D / 4;
            if (g2 < N_SUP * D * D) {
                int j    = g2 & 7;
                int lane = (g2 >> 3) & 63;
                int rest = g2 >> 9;
                int nt = rest & 7, kb = (rest >> 3) & 3, s = rest >> 5;
                int k = kb * 32 + ((lane >> 4) * 8) + j;
                int n = nt * 16 + (lane & 15);
                Wf[g2] = f2bf(W[((size_t)s * D + k) * D + n]);
            }
        }
        return;
    }

    // ------------------------------- sort path ----------------------------
    int c   = blockIdx.x;
    int cnt = coarse_wptr[c * 16];
    if (cnt > CAPC) cnt = CAPC;

    __shared__ int hist[512];
    __shared__ int rank[512];
    __shared__ int wsum[8];
    int lane = tid & 63;
    int w    = tid >> 6;
    hist[tid] = 0;

    const uint2* src = sortedA + (size_t)c * CAPC;
    uint2 e[15];
    #pragma unroll
    for (int k = 0; k < 15; ++k) {               // independent loads
        int idx = tid + k * 512;
        if (idx < cnt) e[k] = src[idx];
    }
    __syncthreads();
    #pragma unroll
    for (int k = 0; k < 15; ++k) {
        int idx = tid + k * 512;
        if (idx < cnt) atomicAdd(&hist[e[k].x >> 16], 1);
    }
    __syncthreads();

    int cntb = hist[tid];
    int v = cntb;                                // wave inclusive scan
    #pragma unroll
    for (int d = 1; d < 64; d <<= 1) {
        int t = __shfl_up(v, d);
        v += (lane >= d) ? t : 0;
    }
    if (lane == 63) wsum[w] = v;
    __syncthreads();
    int add = 0;
    #pragma unroll
    for (int i = 0; i < 8; ++i) add += (i < w) ? wsum[i] : 0;
    int incl = v + add;

    int start = c * CAPC + incl - cntb;          // exclusive, bucket-based
    rank[tid] = start;
    row_ptr2[c * 513 + tid] = start;
    if (tid == 511) row_ptr2[c * 513 + 512] = c * CAPC + incl;
    __syncthreads();

    #pragma unroll
    for (int k = 0; k < 15; ++k) {
        int idx = tid + k * 512;
        if (idx < cnt) {
            int r = atomicAdd(&rank[e[k].x >> 16], 1);
            sortedB[r] = (e[k].y & 0xFFFF0000u) | (e[k].x & 0xFFFFu);
        }
    }
}

// ---------------------------------------------------------------------------
// FUSED gather + MFMA GEMM. Phase 1 RESTRUCTURED for memory-level
// parallelism: the old layout held only 2 outstanding 8-B x-loads per wave
// and spent ~25 VALU + 2 shfl per 4 edges (latency-bound: MfmaUtil 2.5%,
// VALUBusy 41%, HBM 34%). New layout: 4 groups of 16 lanes per wave; group
// G owns node m0+G's rows {G, G+16, G+32} (3 supports). Per edge the group
// reads the full 256-B x-row as ONE dwordx4/lane (wave instr = 4 edges =
// 1 KB), quartet-unrolled for 4+ loads in flight, each lane accumulates its
// own 8 dims -> no cross-lane reduction at all. Phase 2 MFMA untouched.
// ---------------------------------------------------------------------------
__global__ __launch_bounds__(256) void gather_gemm(
    const unsigned short* __restrict__ xb, const int* __restrict__ row_ptr2,
    const unsigned int* __restrict__ sortedB,
    const unsigned short* __restrict__ Wf,
    const float* __restrict__ bias, float* __restrict__ out)
{
    __shared__ unsigned short ys[48 * LDSTR];    // 12.7 KB
    __shared__ int rs[48], re[48];
    const int tid  = threadIdx.x;
    const int w    = tid >> 6;
    const int lane = tid & 63;
    const int m0   = blockIdx.x * 16;

    if (tid < 48) {
        int grow = (tid >> 4) * N_NODES + m0 + (tid & 15);
        int rpi  = (grow >> 9) * 513 + (grow & 511);
        rs[tid] = row_ptr2[rpi];
        re[tid] = row_ptr2[rpi + 1];
    }
    __syncthreads();

    // ---- phase 1: group-per-row gather ----
    const int gl = lane & 15;                    // lane in group: dims gl*8..+7
    const int G  = w * 4 + (lane >> 4);          // group id = node index 0..15
    const unsigned int gsel = (unsigned int)(lane & 48);  // group base lane

    #pragma unroll
    for (int sp = 0; sp < N_SUP; ++sp) {
        int r = sp * 16 + G;
        int start = rs[r], end = re[r];
        f32x2 a0 = {0.f, 0.f}, a1 = {0.f, 0.f};
        f32x2 a2 = {0.f, 0.f}, a3 = {0.f, 0.f};

        for (int j = start; j < end; j += 16) {  // 16-edge chunks
            unsigned int ev = (j + gl < end) ? sortedB[j + gl] : 0u;
            #pragma unroll
            for (int tq = 0; tq < 4; ++tq) {     // quartets: 4 indep loads
                if (j + tq * 4 < end) {
                    #pragma unroll
                    for (int t4 = 0; t4 < 4; ++t4) {
                        unsigned int e = (unsigned int)
                            __shfl((int)ev, (int)(gsel + tq * 4 + t4));
                        float v = __uint_as_float(e & 0xFFFF0000u);
                        // dummy slots: e=0 -> v=0, col=0 (harmless hot read)
                        uint4 X = *((const uint4*)(xb + (size_t)(e & 0xFFFFu) * D) + gl);
                        f32x2 vv = {v, v};
                        f32x2 x0 = {__uint_as_float(X.x << 16),
                                    __uint_as_float(X.x & 0xFFFF0000u)};
                        f32x2 x1 = {__uint_as_float(X.y << 16),
                                    __uint_as_float(X.y & 0xFFFF0000u)};
                        f32x2 x2 = {__uint_as_float(X.z << 16),
                                    __uint_as_float(X.z & 0xFFFF0000u)};
                        f32x2 x3 = {__uint_as_float(X.w << 16),
                                    __uint_as_float(X.w & 0xFFFF0000u)};
                        a0 += vv * x0;           // v_pk_fma_f32
                        a1 += vv * x1;
                        a2 += vv * x2;
                        a3 += vv * x3;
                    }
                }
            }
        }
        uint2 o0, o1;
        o0.x = (unsigned int)f2bf(a0.x) | ((unsigned int)f2bf(a0.y) << 16);
        o0.y = (unsigned int)f2bf(a1.x) | ((unsigned int)f2bf(a1.y) << 16);
        o1.x = (unsigned int)f2bf(a2.x) | ((unsigned int)f2bf(a2.y) << 16);
        o1.y = (unsigned int)f2bf(a3.x) | ((unsigned int)f2bf(a3.y) << 16);
        *(uint2*)(ys + r * LDSTR + gl * 8)     = o0;   // 8B-aligned
        *(uint2*)(ys + r * LDSTR + gl * 8 + 4) = o1;
    }
    __syncthreads();

    // ---- phase 2: MFMA GEMM, wave w -> nt {2w, 2w+1} (untouched) ----
    const int quad = lane >> 4;
    const int l16  = lane & 15;
    const int nt0  = w * 2;
    f32x4 acc0 = {0.f, 0.f, 0.f, 0.f}, acc1 = {0.f, 0.f, 0.f, 0.f};

    #pragma unroll
    for (int s = 0; s < N_SUP; ++s) {
        #pragma unroll
        for (int kb = 0; kb < 4; ++kb) {
            union { uint2 q[2]; s16x8 v; } A;
            const unsigned short* ap = ys + (s * 16 + l16) * LDSTR
                                          + kb * 32 + quad * 8;
            A.q[0] = *(const uint2*)ap;          // 8B-aligned LDS reads
            A.q[1] = *(const uint2*)(ap + 4);
            const unsigned short* wf = Wf + (size_t)((s * 4 + kb) * 8 + nt0) * 64 * 8
                                          + lane * 8;
            s16x8 b0 = *(const s16x8*)wf;
            s16x8 b1 = *(const s16x8*)(wf + 64 * 8);
            acc0 = __builtin_amdgcn_mfma_f32_16x16x32_bf16(A.v, b0, acc0, 0, 0, 0);
            acc1 = __builtin_amdgcn_mfma_f32_16x16x32_bf16(A.v, b1, acc1, 0, 0, 0);
        }
    }

    #pragma unroll
    for (int p = 0; p < 2; ++p) {
        int col = (nt0 + p) * 16 + l16;
        float bv = bias[col];
        f32x4 a = p ? acc1 : acc0;
        #pragma unroll
        for (int r = 0; r < 4; ++r) {
            int row = m0 + quad * 4 + r;
            out[(size_t)row * D + col] = fmaxf(a[r] + bv, 0.f);
        }
    }
}

extern "C" void kernel_launch(void* const* d_in, const int* in_sizes, int n_in,
                              void* d_out, int out_size, void* d_ws, size_t ws_size,
                              hipStream_t stream)
{
    const float* x         = (const float*)d_in[0];
    const int*   edge_rows = (const int*)  d_in[1];
    const int*   edge_cols = (const int*)  d_in[2];
    const float* edge_vals = (const float*)d_in[3];
    const float* weights   = (const float*)d_in[4];
    const float* bias      = (const float*)d_in[5];
    float* out = (float*)d_out;

    // workspace layout (256B aligned), ~40 MB total
    char* ws = (char*)d_ws;
    size_t off = 0;
    auto alloc = [&](size_t bytes) -> char* {
        char* p = ws + off;
        off += (bytes + 255) & ~(size_t)255;
        return p;
    };
    int*            coarse_wptr = (int*)            alloc(512 * 16 * 4);
    int*            row_ptr2    = (int*)            alloc((size_t)NC * 513 * 4);
    unsigned short* xb          = (unsigned short*) alloc((size_t)N_NODES * D * 2);
    unsigned short* Wf          = (unsigned short*) alloc((size_t)N_SUP * D * D * 2);
    uint2*          sortedA     = (uint2*)          alloc((size_t)NC * CAPC * 8);
    unsigned int*   sortedB     = (unsigned int*)   alloc((size_t)NC * CAPC * 4);

    hipMemsetAsync(coarse_wptr, 0, 512 * 16 * 4, stream);
    prep_scatter<<<SBLKS, 512, 0, stream>>>(
        edge_rows, edge_cols, edge_vals, coarse_wptr, sortedA);
    sort_convert<<<NC + XCBLKS + WBLKS, 512, 0, stream>>>(
        coarse_wptr, sortedA, row_ptr2, sortedB,
        (const float4*)x, (ushort4*)xb, weights, Wf);
    gather_gemm<<<N_NODES / 16, 256, 0, stream>>>(xb, row_ptr2, sortedB,
                                                  Wf, bias, out);
}

// Round 7
// 182.859 us; speedup vs baseline: 1.1034x; 1.0215x over previous
//
#include <hip/hip_runtime.h>

#define N_NODES 50000
#define N_EDGES 640000
#define N_SUP   3
#define D       128
#define NTOT    150000                   // 3 * 50000 global rows
#define E_TOT   1920000
#define NC      293                      // 512-row coarse buckets (grow>>9)
#define CAPC    7680                     // per-bucket cap: mean 6553 + ~14 sigma
#define CTILE   2048
#define CTPS    313                      // ceil(640000/2048) tiles per support
#define SBLKS   (N_SUP * CTPS)           // 939 edge tiles
#define XCBLKS  3125                     // (50000*128/4)/512 x-convert blocks
#define WBLKS   96                       // 49152/512 W-pack blocks
#define LDSTR   132                      // LDS row stride in shorts (128+4 pad)

typedef __attribute__((ext_vector_type(2))) float f32x2;
typedef __attribute__((ext_vector_type(4))) float f32x4;
typedef __attribute__((ext_vector_type(8))) short s16x8;

__device__ __forceinline__ unsigned short f2bf(float f) {   // RNE
    unsigned int u = __float_as_uint(f);
    u += 0x7FFFu + ((u >> 16) & 1u);
    return (unsigned short)(u >> 16);
}

// ---------------------------------------------------------------------------
// Pass 1: coarse scatter (R5-proven, untouched). LDS-staged bucket-sorted
// runs, atomic global bucket bases, uint2 staged edges.
// ---------------------------------------------------------------------------
__global__ __launch_bounds__(512) void prep_scatter(
    const int* __restrict__ rows, const int* __restrict__ cols,
    const float* __restrict__ vals, int* __restrict__ coarse_wptr,
    uint2* __restrict__ sortedA)
{
    __shared__ int          h[512];              // bucket histogram
    __shared__ int          toff[512];           // tile-local bucket offsets
    __shared__ int          gbase[512];          // global bucket bases
    __shared__ int          wsum[8];
    __shared__ uint2        stage[CTILE];        // 16 KB bucket-sorted edges
    __shared__ unsigned int dst[CTILE];          // 8 KB absolute dests

    int tid  = threadIdx.x;
    const int lane = tid & 63;
    const int w    = tid >> 6;

    h[tid] = 0;
    __syncthreads();

    int s  = blockIdx.x / CTPS;
    int tb = (blockIdx.x % CTPS) * CTILE;
    int n  = N_EDGES - tb; if (n > CTILE) n = CTILE;
    const int*   rp = rows + (size_t)s * N_EDGES + tb;
    const int*   cp = cols + (size_t)s * N_EDGES + tb;
    const float* vp = vals + (size_t)s * N_EDGES + tb;

    int bk[4], rk[4]; uint2 ed[4];
    #pragma unroll
    for (int i = 0; i < 4; ++i) {
        int idx = tid + i * 512;
        bk[i] = -1;
        if (idx < n) {
            int grow = s * N_NODES + rp[idx];
            bk[i] = grow >> 9;
            rk[i] = atomicAdd(&h[bk[i]], 1);     // within-tile bucket rank (LDS)
            ed[i] = make_uint2(((unsigned int)(grow & 511) << 16)
                               | (unsigned int)cp[idx],
                               (unsigned int)f2bf(vp[idx]) << 16);
        }
    }
    __syncthreads();
    int cntb = h[tid];

    int v = cntb;                                // wave inclusive scan
    #pragma unroll
    for (int d = 1; d < 64; d <<= 1) {
        int t = __shfl_up(v, d);
        v += (lane >= d) ? t : 0;
    }
    if (lane == 63) wsum[w] = v;
    __syncthreads();
    int add = 0;
    #pragma unroll
    for (int i = 0; i < 8; ++i) add += (i < w) ? wsum[i] : 0;
    int incl = v + add;

    toff[tid]  = incl - cntb;                    // tile-local exclusive
    gbase[tid] = (cntb > 0) ? atomicAdd(&coarse_wptr[tid * 16], cntb) : 0;
    __syncthreads();

    #pragma unroll
    for (int i = 0; i < 4; ++i) {
        if (bk[i] >= 0) {
            int slot  = toff[bk[i]] + rk[i];
            int gslot = gbase[bk[i]] + rk[i];
            stage[slot] = ed[i];
            dst[slot] = (gslot < CAPC)
                      ? (unsigned int)(bk[i] * CAPC + gslot)
                      : 0xFFFFFFFFu;             // never at +14 sigma
        }
    }
    __syncthreads();
    for (int j = tid; j < n; j += 512) {         // coalesced run writes
        unsigned int d = dst[j];
        if (d != 0xFFFFFFFFu) sortedA[d] = stage[j];
    }
}

// ---------------------------------------------------------------------------
// Pass 2: fine sort co-launched with converts (R5-proven, untouched).
// ---------------------------------------------------------------------------
__global__ __launch_bounds__(512) void sort_convert(
    const int* __restrict__ coarse_wptr, const uint2* __restrict__ sortedA,
    int* __restrict__ row_ptr2, unsigned int* __restrict__ sortedB,
    const float4* __restrict__ x, ushort4* __restrict__ xb,
    const float* __restrict__ W, unsigned short* __restrict__ Wf)
{
    int tid = threadIdx.x;

    if (blockIdx.x >= NC) {                      // -------- convert path ----
        int gid = (blockIdx.x - NC) * 512 + tid;
        if (gid < N_NODES * D / 4) {             // x -> bf16
            float4 v = x[gid];
            ushort4 o;
            o.x = f2bf(v.x); o.y = f2bf(v.y); o.z = f2bf(v.z); o.w = f2bf(v.w);
            xb[gid] = o;
        } else {                                 // W -> MFMA B-fragment order
            int g2 = gid - N_NODES * D / 4;
            if (g2 < N_SUP * D * D) {
                int j    = g2 & 7;
                int lane = (g2 >> 3) & 63;
                int rest = g2 >> 9;
                int nt = rest & 7, kb = (rest >> 3) & 3, s = rest >> 5;
                int k = kb * 32 + ((lane >> 4) * 8) + j;
                int n = nt * 16 + (lane & 15);
                Wf[g2] = f2bf(W[((size_t)s * D + k) * D + n]);
            }
        }
        return;
    }

    // ------------------------------- sort path ----------------------------
    int c   = blockIdx.x;
    int cnt = coarse_wptr[c * 16];
    if (cnt > CAPC) cnt = CAPC;

    __shared__ int hist[512];
    __shared__ int rank[512];
    __shared__ int wsum[8];
    int lane = tid & 63;
    int w    = tid >> 6;
    hist[tid] = 0;

    const uint2* src = sortedA + (size_t)c * CAPC;
    uint2 e[15];
    #pragma unroll
    for (int k = 0; k < 15; ++k) {               // independent loads
        int idx = tid + k * 512;
        if (idx < cnt) e[k] = src[idx];
    }
    __syncthreads();
    #pragma unroll
    for (int k = 0; k < 15; ++k) {
        int idx = tid + k * 512;
        if (idx < cnt) atomicAdd(&hist[e[k].x >> 16], 1);
    }
    __syncthreads();

    int cntb = hist[tid];
    int v = cntb;                                // wave inclusive scan
    #pragma unroll
    for (int d = 1; d < 64; d <<= 1) {
        int t = __shfl_up(v, d);
        v += (lane >= d) ? t : 0;
    }
    if (lane == 63) wsum[w] = v;
    __syncthreads();
    int add = 0;
    #pragma unroll
    for (int i = 0; i < 8; ++i) add += (i < w) ? wsum[i] : 0;
    int incl = v + add;

    int start = c * CAPC + incl - cntb;          // exclusive, bucket-based
    rank[tid] = start;
    row_ptr2[c * 513 + tid] = start;
    if (tid == 511) row_ptr2[c * 513 + 512] = c * CAPC + incl;
    __syncthreads();

    #pragma unroll
    for (int k = 0; k < 15; ++k) {
        int idx = tid + k * 512;
        if (idx < cnt) {
            int r = atomicAdd(&rank[e[k].x >> 16], 1);
            sortedB[r] = (e[k].y & 0xFFFF0000u) | (e[k].x & 0xFFFFu);
        }
    }
}

// ---------------------------------------------------------------------------
// FUSED gather + MFMA GEMM. Phase 1 now MAX-MLP: R6's quartet loop consumed
// each dwordx4 right after issue (~4 outstanding). Here two quartets ping-
// pong (8 loads in flight: issue Q0+Q1, consume Q0, reissue Q2, consume Q1,
// reissue Q3, ...) and the next chunk's sortedB word is prefetched before
// the FMAs. All register-array indices compile-time (no scratch). This is
// the H1/H2 discriminator: if dur doesn't move with FETCH unchanged, the
// beyond-L2 path is saturated and gather is at its algorithmic roofline.
// Phase 2 MFMA untouched.
// ---------------------------------------------------------------------------
#define LOADQ(EARR, XARR, TQ)                                                  \
    _Pragma("unroll")                                                          \
    for (int t = 0; t < 4; ++t) {                                              \
        EARR[t] = (unsigned int)__shfl((int)ev, (int)(gsel + (TQ) * 4 + t));   \
        XARR[t] = *((const uint4*)(xb + (size_t)(EARR[t] & 0xFFFFu) * D) + gl);\
    }

#define FMAQ(EARR, XARR)                                                       \
    _Pragma("unroll")                                                          \
    for (int t = 0; t < 4; ++t) {                                              \
        float v = __uint_as_float(EARR[t] & 0xFFFF0000u);                      \
        f32x2 vv = {v, v};                                                     \
        f32x2 x0 = {__uint_as_float(XARR[t].x << 16),                          \
                    __uint_as_float(XARR[t].x & 0xFFFF0000u)};                 \
        f32x2 x1 = {__uint_as_float(XARR[t].y << 16),                          \
                    __uint_as_float(XARR[t].y & 0xFFFF0000u)};                 \
        f32x2 x2 = {__uint_as_float(XARR[t].z << 16),                          \
                    __uint_as_float(XARR[t].z & 0xFFFF0000u)};                 \
        f32x2 x3 = {__uint_as_float(XARR[t].w << 16),                          \
                    __uint_as_float(XARR[t].w & 0xFFFF0000u)};                 \
        a0 += vv * x0; a1 += vv * x1; a2 += vv * x2; a3 += vv * x3;            \
    }

__global__ __launch_bounds__(256, 4) void gather_gemm(
    const unsigned short* __restrict__ xb, const int* __restrict__ row_ptr2,
    const unsigned int* __restrict__ sortedB,
    const unsigned short* __restrict__ Wf,
    const float* __restrict__ bias, float* __restrict__ out)
{
    __shared__ unsigned short ys[48 * LDSTR];    // 12.7 KB
    __shared__ int rs[48], re[48];
    const int tid  = threadIdx.x;
    const int w    = tid >> 6;
    const int lane = tid & 63;
    const int m0   = blockIdx.x * 16;

    if (tid < 48) {
        int grow = (tid >> 4) * N_NODES + m0 + (tid & 15);
        int rpi  = (grow >> 9) * 513 + (grow & 511);
        rs[tid] = row_ptr2[rpi];
        re[tid] = row_ptr2[rpi + 1];
    }
    __syncthreads();

    // ---- phase 1: group-per-row gather, ping-pong pipelined ----
    const int gl = lane & 15;                    // lane in group: dims gl*8..+7
    const int G  = w * 4 + (lane >> 4);          // group id = node index 0..15
    const unsigned int gsel = (unsigned int)(lane & 48);  // group base lane

    #pragma unroll
    for (int sp = 0; sp < N_SUP; ++sp) {
        int r = sp * 16 + G;
        int start = rs[r], end = re[r];
        f32x2 a0 = {0.f, 0.f}, a1 = {0.f, 0.f};
        f32x2 a2 = {0.f, 0.f}, a3 = {0.f, 0.f};

        unsigned int ev = (start + gl < end) ? sortedB[start + gl] : 0u;
        for (int j = start; j < end; j += 16) {  // 16-edge chunks
            unsigned int evn = (j + 16 + gl < end) ? sortedB[j + 16 + gl] : 0u;
            bool q1 = (j + 4 < end), q2 = (j + 8 < end), q3 = (j + 12 < end);
            unsigned int eA[4], eB[4];
            uint4 XA[4], XB[4];
            LOADQ(eA, XA, 0);                    // 4 loads in flight
            if (q1) LOADQ(eB, XB, 1);            // 8 in flight
            FMAQ(eA, XA);                        // consume Q0
            if (q2) LOADQ(eA, XA, 2);            // refill
            if (q1) FMAQ(eB, XB);                // consume Q1
            if (q3) LOADQ(eB, XB, 3);            // refill
            if (q2) FMAQ(eA, XA);                // consume Q2
            if (q3) FMAQ(eB, XB);                // consume Q3
            ev = evn;
        }
        uint2 o0, o1;
        o0.x = (unsigned int)f2bf(a0.x) | ((unsigned int)f2bf(a0.y) << 16);
        o0.y = (unsigned int)f2bf(a1.x) | ((unsigned int)f2bf(a1.y) << 16);
        o1.x = (unsigned int)f2bf(a2.x) | ((unsigned int)f2bf(a2.y) << 16);
        o1.y = (unsigned int)f2bf(a3.x) | ((unsigned int)f2bf(a3.y) << 16);
        *(uint2*)(ys + r * LDSTR + gl * 8)     = o0;   // 8B-aligned
        *(uint2*)(ys + r * LDSTR + gl * 8 + 4) = o1;
    }
    __syncthreads();

    // ---- phase 2: MFMA GEMM, wave w -> nt {2w, 2w+1} (untouched) ----
    const int quad = lane >> 4;
    const int l16  = lane & 15;
    const int nt0  = w * 2;
    f32x4 acc0 = {0.f, 0.f, 0.f, 0.f}, acc1 = {0.f, 0.f, 0.f, 0.f};

    #pragma unroll
    for (int s = 0; s < N_SUP; ++s) {
        #pragma unroll
        for (int kb = 0; kb < 4; ++kb) {
            union { uint2 q[2]; s16x8 v; } A;
            const unsigned short* ap = ys + (s * 16 + l16) * LDSTR
                                          + kb * 32 + quad * 8;
            A.q[0] = *(const uint2*)ap;          // 8B-aligned LDS reads
            A.q[1] = *(const uint2*)(ap + 4);
            const unsigned short* wf = Wf + (size_t)((s * 4 + kb) * 8 + nt0) * 64 * 8
                                          + lane * 8;
            s16x8 b0 = *(const s16x8*)wf;
            s16x8 b1 = *(const s16x8*)(wf + 64 * 8);
            acc0 = __builtin_amdgcn_mfma_f32_16x16x32_bf16(A.v, b0, acc0, 0, 0, 0);
            acc1 = __builtin_amdgcn_mfma_f32_16x16x32_bf16(A.v, b1, acc1, 0, 0, 0);
        }
    }

    #pragma unroll
    for (int p = 0; p < 2; ++p) {
        int col = (nt0 + p) * 16 + l16;
        float bv = bias[col];
        f32x4 a = p ? acc1 : acc0;
        #pragma unroll
        for (int r = 0; r < 4; ++r) {
            int row = m0 + quad * 4 + r;
            out[(size_t)row * D + col] = fmaxf(a[r] + bv, 0.f);
        }
    }
}

extern "C" void kernel_launch(void* const* d_in, const int* in_sizes, int n_in,
                              void* d_out, int out_size, void* d_ws, size_t ws_size,
                              hipStream_t stream)
{
    const float* x         = (const float*)d_in[0];
    const int*   edge_rows = (const int*)  d_in[1];
    const int*   edge_cols = (const int*)  d_in[2];
    const float* edge_vals = (const float*)d_in[3];
    const float* weights   = (const float*)d_in[4];
    const float* bias      = (const float*)d_in[5];
    float* out = (float*)d_out;

    // workspace layout (256B aligned), ~40 MB total
    char* ws = (char*)d_ws;
    size_t off = 0;
    auto alloc = [&](size_t bytes) -> char* {
        char* p = ws + off;
        off += (bytes + 255) & ~(size_t)255;
        return p;
    };
    int*            coarse_wptr = (int*)            alloc(512 * 16 * 4);
    int*            row_ptr2    = (int*)            alloc((size_t)NC * 513 * 4);
    unsigned short* xb          = (unsigned short*) alloc((size_t)N_NODES * D * 2);
    unsigned short* Wf          = (unsigned short*) alloc((size_t)N_SUP * D * D * 2);
    uint2*          sortedA     = (uint2*)          alloc((size_t)NC * CAPC * 8);
    unsigned int*   sortedB     = (unsigned int*)   alloc((size_t)NC * CAPC * 4);

    hipMemsetAsync(coarse_wptr, 0, 512 * 16 * 4, stream);
    prep_scatter<<<SBLKS, 512, 0, stream>>>(
        edge_rows, edge_cols, edge_vals, coarse_wptr, sortedA);
    sort_convert<<<NC + XCBLKS + WBLKS, 512, 0, stream>>>(
        coarse_wptr, sortedA, row_ptr2, sortedB,
        (const float4*)x, (ushort4*)xb, weights, Wf);
    gather_gemm<<<N_NODES / 16, 256, 0, stream>>>(xb, row_ptr2, sortedB,
                                                  Wf, bias, out);
}